// Round 1
// baseline (485.801 us; speedup 1.0000x reference)
//
#include <hip/hip_runtime.h>
#include <hip/hip_bf16.h>
#include <math.h>

// Problem constants: B=8, CIN=64, COUT=64, N=16, H=W=32
// ws layout (floats):
//   zxy  @ 0        (1024*8)
//   zhw  @ 8192     (1024*8)
//   A2   @ 16384    (64*576)   rows o, cols j: j<512 -> Q[o,i,k]/1024 (j=i*8+k), j>=512 -> conv_w[o][j-512]
//   Vsum @ 53248    (512)      sum_xy v[b,i,xy]
//   E    @ 53760    (512)      conv_b[o]+bias[o]+(1/1024)*sum_i r[o,i]*Vsum[b,i]
//   G    @ 54272    (1024*8192)  G[xy][k*1024+hw] = gelu(zxy[xy,k]+zhw[hw,k])
//   S    @ 8442880  (512*8192)   S[bi][k*1024+hw]  == (b,i,k,hw) contiguous
// total 12,637,184 floats = 50.5 MB

#define WS_ZXY   0
#define WS_ZHW   8192
#define WS_A2    16384
#define WS_VSUM  53248
#define WS_E     53760
#define WS_G     54272
#define WS_S     8442880

__global__ void prep_kernel(const float* __restrict__ params, const float* __restrict__ w1,
                            const float* __restrict__ b1, const float* __restrict__ w2,
                            const float* __restrict__ conv_w, float* __restrict__ ws) {
    float* zxy = ws + WS_ZXY;
    float* zhw = ws + WS_ZHW;
    float* A2  = ws + WS_A2;
    for (int t = blockIdx.x * 256 + threadIdx.x; t < 53248; t += gridDim.x * 256) {
        if (t < 8192) {
            int xy = t >> 3, k = t & 7;
            float cx = 2.0f * (((xy >> 5) + 0.5f) / 32.0f) - 1.0f;
            float cy = 2.0f * (((xy & 31) + 0.5f) / 32.0f) - 1.0f;
            zxy[t] = cx * w1[k * 4 + 0] + cy * w1[k * 4 + 1] + b1[k];
        } else if (t < 16384) {
            int u = t - 8192;
            int hw = u >> 3, k = u & 7;
            float ch = 2.0f * (((hw >> 5) + 0.5f) / 32.0f) - 1.0f;
            float cw = 2.0f * (((hw & 31) + 0.5f) / 32.0f) - 1.0f;
            zhw[u] = ch * w1[k * 4 + 2] + cw * w1[k * 4 + 3];
        } else {
            int u = t - 16384;          // u = o*576 + j
            int o = u / 576, j = u % 576;
            float val;
            if (j < 512) {
                int i = j >> 3, k = j & 7;
                float s = 0.0f;
                #pragma unroll
                for (int n = 0; n < 16; n++)
                    s += params[n * 4096 + o * 64 + i] * w2[n * 8 + k];
                val = s * (1.0f / 1024.0f);
            } else {
                val = conv_w[o * 64 + (j - 512)];
            }
            A2[u] = val;
        }
    }
}

// one wave per (b,i): Vsum[bi] = sum_xy v[b,i,xy]
__global__ void vsum_kernel(const float* __restrict__ v, float* __restrict__ ws) {
    float* Vsum = ws + WS_VSUM;
    int bi = blockIdx.x;
    int lane = threadIdx.x;
    const float* p = v + bi * 1024;
    float s = 0.0f;
    #pragma unroll
    for (int t = 0; t < 16; t++) s += p[lane + t * 64];
    #pragma unroll
    for (int off = 32; off > 0; off >>= 1) s += __shfl_down(s, off);
    if (lane == 0) Vsum[bi] = s;
}

__global__ void e_kernel(const float* __restrict__ params, const float* __restrict__ b2,
                         const float* __restrict__ conv_b, const float* __restrict__ bias,
                         float* __restrict__ ws) {
    const float* Vsum = ws + WS_VSUM;
    float* E = ws + WS_E;
    int t = threadIdx.x;            // b*64 + o
    int b = t >> 6, o = t & 63;
    float s = 0.0f;
    for (int i = 0; i < 64; i++) {
        float r = 0.0f;
        #pragma unroll
        for (int n = 0; n < 16; n++)
            r += params[n * 4096 + o * 64 + i] * b2[n];
        s += r * Vsum[b * 64 + i];
    }
    E[t] = conv_b[o] + bias[o] + s * (1.0f / 1024.0f);
}

// G[xy][k*1024+hw] = gelu_exact(zxy[xy,k] + zhw[hw,k]); 8.4M elements
__global__ void g_kernel(float* __restrict__ ws) {
    const float* zxy = ws + WS_ZXY;
    const float* zhw = ws + WS_ZHW;
    float* G = ws + WS_G;
    int idx = blockIdx.x * 256 + threadIdx.x;   // = xy*8192 + k*1024 + hw
    int hw = idx & 1023;
    int k = (idx >> 10) & 7;
    int xy = idx >> 13;
    float z = zxy[xy * 8 + k] + zhw[hw * 8 + k];
    G[idx] = 0.5f * z * (1.0f + erff(z * 0.70710678118f));
}

// SGEMM-2: S(512 x 8192) = v(512 x 1024) @ G(1024 x 8192)
// BM=128 BN=128 BK=16, 256 threads, 8x8 micro-tile; LDS stride 132 (pad 4, keeps 16B align)
__global__ __launch_bounds__(256) void gemm2_kernel(const float* __restrict__ v,
                                                    float* __restrict__ ws) {
    const float* G = ws + WS_G;
    float* S = ws + WS_S;
    __shared__ float As[16 * 132];
    __shared__ float Bs[16 * 132];
    int tid = threadIdx.x;
    int bn = blockIdx.x;            // 0..63
    int bm = blockIdx.y;            // 0..3
    int tx = tid & 15, ty = tid >> 4;
    float acc[8][8] = {};
    const float* Abase = v + bm * 128 * 1024;
    const float* Bbase = G + bn * 128;

    for (int k0 = 0; k0 < 1024; k0 += 16) {
        #pragma unroll
        for (int l = 0; l < 2; l++) {
            int f = tid + l * 256;          // 0..511
            int r = f >> 2, c4 = f & 3;
            float4 a = *(const float4*)(Abase + r * 1024 + k0 + c4 * 4);
            As[(c4 * 4 + 0) * 132 + r] = a.x;
            As[(c4 * 4 + 1) * 132 + r] = a.y;
            As[(c4 * 4 + 2) * 132 + r] = a.z;
            As[(c4 * 4 + 3) * 132 + r] = a.w;
        }
        #pragma unroll
        for (int l = 0; l < 2; l++) {
            int f = tid + l * 256;
            int r = f >> 5, c4 = f & 31;
            float4 bvec = *(const float4*)(Bbase + (k0 + r) * 8192 + c4 * 4);
            *(float4*)(&Bs[r * 132 + c4 * 4]) = bvec;
        }
        __syncthreads();
        #pragma unroll
        for (int kk = 0; kk < 16; kk++) {
            float a[8], bb[8];
            *(float4*)(a)      = *(const float4*)(&As[kk * 132 + ty * 8]);
            *(float4*)(a + 4)  = *(const float4*)(&As[kk * 132 + ty * 8 + 4]);
            *(float4*)(bb)     = *(const float4*)(&Bs[kk * 132 + tx * 8]);
            *(float4*)(bb + 4) = *(const float4*)(&Bs[kk * 132 + tx * 8 + 4]);
            #pragma unroll
            for (int i = 0; i < 8; i++)
                #pragma unroll
                for (int j = 0; j < 8; j++)
                    acc[i][j] += a[i] * bb[j];
        }
        __syncthreads();
    }
    #pragma unroll
    for (int i = 0; i < 8; i++) {
        int row = bm * 128 + ty * 8 + i;
        float* dst = S + (size_t)row * 8192 + bn * 128 + tx * 8;
        *(float4*)(dst)     = make_float4(acc[i][0], acc[i][1], acc[i][2], acc[i][3]);
        *(float4*)(dst + 4) = make_float4(acc[i][4], acc[i][5], acc[i][6], acc[i][7]);
    }
}

// SGEMM-3 + epilogue: per b: out(64 x 1024) = A2(64 x 576) @ [S_b(512x1024); v_b(64x1024)] + E
// BM=64 BN=64 BK=16, 256 threads, 4x4 micro-tile; LDS stride 68
__global__ __launch_bounds__(256) void gemm3_kernel(const float* __restrict__ v,
                                                    float* __restrict__ out,
                                                    const float* __restrict__ ws) {
    const float* A2 = ws + WS_A2;
    const float* E = ws + WS_E;
    const float* S = ws + WS_S;
    __shared__ float As[16 * 68];
    __shared__ float Bs[16 * 68];
    int tid = threadIdx.x;
    int bn = blockIdx.x;            // hw tile 0..15
    int b  = blockIdx.y;            // 0..7
    int tx = tid & 15, ty = tid >> 4;
    float acc[4][4] = {};
    const float* Sb = S + (size_t)b * 524288;
    const float* Vb = v + b * 65536;

    for (int k0 = 0; k0 < 576; k0 += 16) {
        {   // A tile: 64 rows x 16 cols
            int r = tid >> 2, c4 = tid & 3;
            float4 a = *(const float4*)(A2 + r * 576 + k0 + c4 * 4);
            As[(c4 * 4 + 0) * 68 + r] = a.x;
            As[(c4 * 4 + 1) * 68 + r] = a.y;
            As[(c4 * 4 + 2) * 68 + r] = a.z;
            As[(c4 * 4 + 3) * 68 + r] = a.w;
        }
        {   // X tile: 16 rows x 64 cols; rows <512 from S_b, >=512 from v_b
            int r = tid >> 4, c4 = tid & 15;
            int j = k0 + r;
            const float* src = (j < 512) ? (Sb + j * 1024) : (Vb + (j - 512) * 1024);
            float4 x = *(const float4*)(src + bn * 64 + c4 * 4);
            *(float4*)(&Bs[r * 68 + c4 * 4]) = x;
        }
        __syncthreads();
        #pragma unroll
        for (int kk = 0; kk < 16; kk++) {
            float a[4], bb[4];
            *(float4*)(a)  = *(const float4*)(&As[kk * 68 + ty * 4]);
            *(float4*)(bb) = *(const float4*)(&Bs[kk * 68 + tx * 4]);
            #pragma unroll
            for (int i = 0; i < 4; i++)
                #pragma unroll
                for (int j = 0; j < 4; j++)
                    acc[i][j] += a[i] * bb[j];
        }
        __syncthreads();
    }
    #pragma unroll
    for (int i = 0; i < 4; i++) {
        int o = ty * 4 + i;
        float e = E[b * 64 + o];
        float* dst = out + b * 65536 + o * 1024 + bn * 64 + tx * 4;
        *(float4*)dst = make_float4(acc[i][0] + e, acc[i][1] + e, acc[i][2] + e, acc[i][3] + e);
    }
}

extern "C" void kernel_launch(void* const* d_in, const int* in_sizes, int n_in,
                              void* d_out, int out_size, void* d_ws, size_t ws_size,
                              hipStream_t stream) {
    const float* v      = (const float*)d_in[0];
    const float* params = (const float*)d_in[1];
    const float* w1     = (const float*)d_in[2];
    const float* b1     = (const float*)d_in[3];
    const float* w2     = (const float*)d_in[4];
    const float* b2     = (const float*)d_in[5];
    const float* conv_w = (const float*)d_in[6];
    const float* conv_b = (const float*)d_in[7];
    const float* bias   = (const float*)d_in[8];
    float* out = (float*)d_out;
    float* ws  = (float*)d_ws;

    prep_kernel<<<208, 256, 0, stream>>>(params, w1, b1, w2, conv_w, ws);
    vsum_kernel<<<512, 64, 0, stream>>>(v, ws);
    e_kernel<<<1, 512, 0, stream>>>(params, b2, conv_b, bias, ws);
    g_kernel<<<32768, 256, 0, stream>>>(ws);
    gemm2_kernel<<<dim3(64, 4), 256, 0, stream>>>(v, ws);
    gemm3_kernel<<<dim3(16, 8), 256, 0, stream>>>(v, out, ws);
}

// Round 2
// 157.852 us; speedup vs baseline: 3.0776x; 3.0776x over previous
//
#include <hip/hip_runtime.h>
#include <hip/hip_bf16.h>
#include <math.h>

// Problem constants: B=8, CIN=64, COUT=64, N=16, H=W=32
//
// Algebra: coeffs(x,y,h,w,n) = gelu(zxy+zhw) @ w2^T + b2  (MLP is separable in coords).
//   t = einsum over n folded into Q[o,i,c] = sum_n params[n,o,i] w2[n,c]  (c = hidden idx, 8)
//   out = A2(64x576) @ [S_b(512x1024); v_b(64x1024)] + E,  S = v(512x1024) @ G(1024x8192)
//   E[b,o] = conv_b+bias + (1/1024) sum_i R[o,i] Vsum[b,i],  R[o,i]=sum_n params b2[n]
//
// ws layout (byte offsets):
#define WSB_ZXY   0u          // 8192 f32   zxy[xy*8+c]
#define WSB_ZHW   32768u      // 8192 f32   zhw[hw*8+c]
#define WSB_A2    65536u      // 64*576 f32 A2[o*576+j]: j<512 -> Q[o,i,c]/1024 (j=i*8+c), else conv_w
#define WSB_VSUM  212992u     // 512 f32    sum_xy v[b,i,xy]
#define WSB_E     215040u     // 512 f32
#define WSB_VH    262144u     // 512*1024 bf16 (v cast)
#define WSB_GH    1310720u    // 8192*1024 bf16, TRANSPOSED: Gh[col*1024+xy], col=c*1024+hw
#define WSB_S     18087936u   // 512*8192 f32: S[(b*64+i)*8192 + c*1024 + hw]
// total 34,865,152 bytes (< round-1's 50.5 MB footprint)

typedef __attribute__((ext_vector_type(8))) short bf16x8;
typedef __attribute__((ext_vector_type(4))) float f32x4;

__device__ inline unsigned short f2bf(float x) {
    unsigned u = __builtin_bit_cast(unsigned, x);
    u += 0x7fff + ((u >> 16) & 1);          // round-to-nearest-even
    return (unsigned short)(u >> 16);
}

__global__ void prep_kernel(const float* __restrict__ params, const float* __restrict__ w1,
                            const float* __restrict__ b1, const float* __restrict__ w2,
                            const float* __restrict__ conv_w, char* __restrict__ wsb) {
    float* zxy = (float*)(wsb + WSB_ZXY);
    float* zhw = (float*)(wsb + WSB_ZHW);
    float* A2  = (float*)(wsb + WSB_A2);
    int t = blockIdx.x * 256 + threadIdx.x;     // grid covers 53248 exactly
    if (t < 8192) {
        int xy = t >> 3, c = t & 7;
        float cx = 2.0f * (((xy >> 5) + 0.5f) / 32.0f) - 1.0f;
        float cy = 2.0f * (((xy & 31) + 0.5f) / 32.0f) - 1.0f;
        zxy[t] = cx * w1[c * 4 + 0] + cy * w1[c * 4 + 1] + b1[c];
    } else if (t < 16384) {
        int u = t - 8192;
        int hw = u >> 3, c = u & 7;
        float ch = 2.0f * (((hw >> 5) + 0.5f) / 32.0f) - 1.0f;
        float cw = 2.0f * (((hw & 31) + 0.5f) / 32.0f) - 1.0f;
        zhw[u] = ch * w1[c * 4 + 2] + cw * w1[c * 4 + 3];
    } else {
        int u = t - 16384;          // u = o*576 + j
        int o = u / 576, j = u % 576;
        float val;
        if (j < 512) {
            int i = j >> 3, c = j & 7;
            float s = 0.0f;
            #pragma unroll
            for (int n = 0; n < 16; n++)
                s += params[n * 4096 + o * 64 + i] * w2[n * 8 + c];
            val = s * (1.0f / 1024.0f);
        } else {
            val = conv_w[o * 64 + (j - 512)];
        }
        A2[u] = val;
    }
}

// one block per (b,i): cast v row to bf16 + row-sum.
__global__ __launch_bounds__(256) void vconv_kernel(const float* __restrict__ v,
                                                    char* __restrict__ wsb) {
    unsigned short* vh = (unsigned short*)(wsb + WSB_VH);
    float* Vsum = (float*)(wsb + WSB_VSUM);
    int bi = blockIdx.x;
    int t = threadIdx.x;
    const float* src = v + bi * 1024;
    float4 x = *(const float4*)(src + t * 4);
    ushort4 h;
    h.x = f2bf(x.x); h.y = f2bf(x.y); h.z = f2bf(x.z); h.w = f2bf(x.w);
    *(ushort4*)(vh + bi * 1024 + t * 4) = h;
    float s = x.x + x.y + x.z + x.w;
    #pragma unroll
    for (int off = 32; off > 0; off >>= 1) s += __shfl_down(s, off);
    __shared__ float red[4];
    if ((t & 63) == 0) red[t >> 6] = s;
    __syncthreads();
    if (t == 0) Vsum[bi] = red[0] + red[1] + red[2] + red[3];
}

// E[b,o] — rebuilt: coalesced cooperative R, LDS-staged, ~3us instead of 225us.
__global__ __launch_bounds__(512) void e_kernel(const float* __restrict__ params,
                                                const float* __restrict__ b2,
                                                const float* __restrict__ conv_b,
                                                const float* __restrict__ bias,
                                                char* __restrict__ wsb) {
    const float* Vsum = (const float*)(wsb + WSB_VSUM);
    float* E = (float*)(wsb + WSB_E);
    __shared__ float Rsh[64 * 65];      // stride 65: bank (o+i)%32, 2-way = free
    __shared__ float Vs[512];
    int t = threadIdx.x;
    float b2r[16];
    #pragma unroll
    for (int n = 0; n < 16; n++) b2r[n] = b2[n];
    for (int j = t; j < 4096; j += 512) {   // coalesced: consecutive lanes -> consecutive j
        float s = 0.0f;
        #pragma unroll
        for (int n = 0; n < 16; n++) s += params[n * 4096 + j] * b2r[n];
        Rsh[(j >> 6) * 65 + (j & 63)] = s;
    }
    Vs[t] = Vsum[t];
    __syncthreads();
    int b = t >> 6, o = t & 63;         // b wave-uniform -> Vs broadcast
    float s = 0.0f;
    for (int i = 0; i < 64; i++) s += Rsh[o * 65 + i] * Vs[b * 64 + i];
    E[t] = conv_b[o] + bias[o] + s * (1.0f / 1024.0f);
}

// Gh[col][xy] bf16, col = c*1024+hw (TRANSPOSED so gemm2 B-frags are contiguous in K=xy)
__global__ __launch_bounds__(256) void g_kernel(char* __restrict__ wsb) {
    const float* zxy = (const float*)(wsb + WSB_ZXY);
    const float* zhw = (const float*)(wsb + WSB_ZHW);
    unsigned short* Gh = (unsigned short*)(wsb + WSB_GH);
    int t = blockIdx.x * 256 + threadIdx.x;     // 0..2^20-1
    int col = t >> 7;
    int xy0 = (t & 127) * 8;
    int c = col >> 10, hw = col & 1023;
    float zz = zhw[hw * 8 + c];
    unsigned short h[8];
    #pragma unroll
    for (int u = 0; u < 8; u++) {
        float z = zxy[(xy0 + u) * 8 + c] + zz;
        h[u] = f2bf(0.5f * z * (1.0f + erff(z * 0.70710678118f)));
    }
    *(uint4*)(Gh + (size_t)col * 1024 + xy0) = *(uint4*)h;
}

// MFMA GEMM: S(512 x 8192) = vh(512 x 1024) @ Gh^T, bf16 in / fp32 acc.
// 64x128 tile, 256 thr (4 waves, each 64m x 32n), BK=32, register-prefetch dbuf.
__global__ __launch_bounds__(256) void gemm2_kernel(char* __restrict__ wsb) {
    const unsigned short* vh = (const unsigned short*)(wsb + WSB_VH);
    const unsigned short* Gh = (const unsigned short*)(wsb + WSB_GH);
    float* S = (float*)(wsb + WSB_S);
    __shared__ short Ash[64 * 32];      // [m][k] row-major, 64B rows
    __shared__ short Bsh[128 * 32];     // [n][k] row-major
    int tid = threadIdx.x;
    int bn = blockIdx.x;                // 0..63
    int bm = blockIdx.y;                // 0..7
    int wave = tid >> 6, lane = tid & 63;
    int lr = lane & 15, quad = lane >> 4;
    f32x4 acc[4][2];
    #pragma unroll
    for (int mt = 0; mt < 4; mt++)
        #pragma unroll
        for (int nt = 0; nt < 2; nt++)
            acc[mt][nt] = (f32x4){0.f, 0.f, 0.f, 0.f};

    const unsigned short* Ab = vh + (size_t)(bm * 64) * 1024;
    const unsigned short* Bb = Gh + (size_t)(bn * 128) * 1024;
    int ar = tid >> 2, aq = tid & 3;    // A: 64 rows x 4 quad-chunks; B rows ar and ar+64

    uint4 pa  = *(const uint4*)(Ab + ar * 1024 + aq * 8);
    uint4 pb0 = *(const uint4*)(Bb + (size_t)ar * 1024 + aq * 8);
    uint4 pb1 = *(const uint4*)(Bb + (size_t)(ar + 64) * 1024 + aq * 8);

    for (int k0 = 0; k0 < 1024; k0 += 32) {
        __syncthreads();
        *(uint4*)(&Ash[tid * 8])         = pa;    // tid*16B linear: conflict-free b128 writes
        *(uint4*)(&Bsh[tid * 8])         = pb0;
        *(uint4*)(&Bsh[(tid + 256) * 8]) = pb1;
        __syncthreads();
        if (k0 + 32 < 1024) {           // prefetch next K-tile; latency overlaps MFMA below
            int k1 = k0 + 32;
            pa  = *(const uint4*)(Ab + ar * 1024 + k1 + aq * 8);
            pb0 = *(const uint4*)(Bb + (size_t)ar * 1024 + k1 + aq * 8);
            pb1 = *(const uint4*)(Bb + (size_t)(ar + 64) * 1024 + k1 + aq * 8);
        }
        bf16x8 a[4], b[2];
        #pragma unroll
        for (int mt = 0; mt < 4; mt++)
            a[mt] = *(bf16x8*)(&Ash[(mt * 16 + lr) * 32 + quad * 8]);
        #pragma unroll
        for (int nt = 0; nt < 2; nt++)
            b[nt] = *(bf16x8*)(&Bsh[(wave * 32 + nt * 16 + lr) * 32 + quad * 8]);
        #pragma unroll
        for (int mt = 0; mt < 4; mt++)
            #pragma unroll
            for (int nt = 0; nt < 2; nt++)
                acc[mt][nt] = __builtin_amdgcn_mfma_f32_16x16x32_bf16(a[mt], b[nt], acc[mt][nt], 0, 0, 0);
    }
    // C/D layout: col = lane&15, row = quad*4 + reg
    #pragma unroll
    for (int mt = 0; mt < 4; mt++) {
        #pragma unroll
        for (int nt = 0; nt < 2; nt++) {
            int n = bn * 128 + wave * 32 + nt * 16 + lr;
            #pragma unroll
            for (int r = 0; r < 4; r++) {
                int m = bm * 64 + mt * 16 + quad * 4 + r;
                S[(size_t)m * 8192 + n] = acc[mt][nt][r];
            }
        }
    }
}

// SGEMM-3 + epilogue (fp32, small): per b: out(64x1024) = A2(64x576) @ [S_b; v_b] + E
__global__ __launch_bounds__(256) void gemm3_kernel(const float* __restrict__ v,
                                                    float* __restrict__ out,
                                                    char* __restrict__ wsb) {
    const float* A2 = (const float*)(wsb + WSB_A2);
    const float* E  = (const float*)(wsb + WSB_E);
    const float* S  = (const float*)(wsb + WSB_S);
    __shared__ float As[16 * 68];
    __shared__ float Bs[16 * 68];
    int tid = threadIdx.x;
    int bn = blockIdx.x;            // hw tile 0..15
    int b  = blockIdx.y;            // 0..7
    int tx = tid & 15, ty = tid >> 4;
    float acc[4][4] = {};
    const float* Sb = S + (size_t)b * 524288;
    const float* Vb = v + b * 65536;

    for (int k0 = 0; k0 < 576; k0 += 16) {
        {   // A tile: 64 rows x 16 cols
            int r = tid >> 2, c4 = tid & 3;
            float4 a = *(const float4*)(A2 + r * 576 + k0 + c4 * 4);
            As[(c4 * 4 + 0) * 68 + r] = a.x;
            As[(c4 * 4 + 1) * 68 + r] = a.y;
            As[(c4 * 4 + 2) * 68 + r] = a.z;
            As[(c4 * 4 + 3) * 68 + r] = a.w;
        }
        {   // X tile: 16 rows x 64 cols; rows <512 from S_b, >=512 from v_b
            int r = tid >> 4, c4 = tid & 15;
            int j = k0 + r;
            const float* src = (j < 512) ? (Sb + (size_t)j * 1024) : (Vb + (j - 512) * 1024);
            float4 x = *(const float4*)(src + bn * 64 + c4 * 4);
            *(float4*)(&Bs[r * 68 + c4 * 4]) = x;
        }
        __syncthreads();
        #pragma unroll
        for (int kk = 0; kk < 16; kk++) {
            float a[4], bb[4];
            *(float4*)(a)  = *(const float4*)(&As[kk * 68 + ty * 4]);
            *(float4*)(bb) = *(const float4*)(&Bs[kk * 68 + tx * 4]);
            #pragma unroll
            for (int i = 0; i < 4; i++)
                #pragma unroll
                for (int j = 0; j < 4; j++)
                    acc[i][j] += a[i] * bb[j];
        }
        __syncthreads();
    }
    #pragma unroll
    for (int i = 0; i < 4; i++) {
        int o = ty * 4 + i;
        float e = E[b * 64 + o];
        float* dst = out + b * 65536 + o * 1024 + bn * 64 + tx * 4;
        *(float4*)dst = make_float4(acc[i][0] + e, acc[i][1] + e, acc[i][2] + e, acc[i][3] + e);
    }
}

extern "C" void kernel_launch(void* const* d_in, const int* in_sizes, int n_in,
                              void* d_out, int out_size, void* d_ws, size_t ws_size,
                              hipStream_t stream) {
    const float* v      = (const float*)d_in[0];
    const float* params = (const float*)d_in[1];
    const float* w1     = (const float*)d_in[2];
    const float* b1     = (const float*)d_in[3];
    const float* w2     = (const float*)d_in[4];
    const float* b2     = (const float*)d_in[5];
    const float* conv_w = (const float*)d_in[6];
    const float* conv_b = (const float*)d_in[7];
    const float* bias   = (const float*)d_in[8];
    float* out = (float*)d_out;
    char* wsb  = (char*)d_ws;

    prep_kernel<<<208, 256, 0, stream>>>(params, w1, b1, w2, conv_w, wsb);
    vconv_kernel<<<512, 256, 0, stream>>>(v, wsb);
    e_kernel<<<1, 512, 0, stream>>>(params, b2, conv_b, bias, wsb);
    g_kernel<<<4096, 256, 0, stream>>>(wsb);
    gemm2_kernel<<<dim3(64, 8), 256, 0, stream>>>(wsb);
    gemm3_kernel<<<dim3(16, 8), 256, 0, stream>>>(v, out, wsb);
}

// Round 4
// 148.710 us; speedup vs baseline: 3.2668x; 1.0615x over previous
//
#include <hip/hip_runtime.h>
#include <hip/hip_bf16.h>
#include <math.h>

// B=8, CIN=64, COUT=64, N=16, H=W=32
// Algebra (MLP separable in coords; n folded into weights):
//   t[b,o,hw]  = sum_{c,xy} P[(b,o),(c,xy)] * G[(c,xy),hw]      (M=512,N=1024,K=8192 MFMA)
//   P[bo,cxy]  = sum_i Qm[o,c,i] * v[b,i,xy]                    (fp32, 537 MFLOP)
//   Qm[o,c,i]  = sum_n params[n,o,i] * w2[n,c] / 1024
//   out = t + conv(v,conv_w) + E;  E[b,o] = conv_b+bias + (1/1024) sum_i R[o,i] Vsum[b,i]
// Big GEMM: split-K 16, fp32 partials; reduce kernel fuses partial-sum + conv + E.
// ws_size = 256 MB (measured from harness poison-fill WRITE_SIZE in round 2); we use 59 MB.
//
// ws layout (byte offsets):
#define WSB_ZXYT 0u          // 8192 f32   zxyT[c*1024+xy]
#define WSB_ZHW  32768u      // 8192 f32   zhw[hw*8+c]
#define WSB_QM   65536u      // 32768 f32  Qm[c*4096 + o*64 + i]
#define WSB_VSUM 196608u     // 512 f32
#define WSB_E    198656u     // 512 f32
#define WSB_GT   262144u     // 1024*8192 bf16  Gt[hw*8192 + c*1024 + xy]   ([n][k])
#define WSB_P    17039360u   // 512*8192 bf16   P[bo*8192 + c*1024 + xy]    ([m][k])
#define WSB_PART 25427968u   // 16*512*1024 f32 part[ks*524288 + bo*1024 + hw]
// total 58,982,400 B

typedef __attribute__((ext_vector_type(8))) short bf16x8;
typedef __attribute__((ext_vector_type(4))) float f32x4;

__device__ inline unsigned short f2bf(float x) {
    unsigned u = __builtin_bit_cast(unsigned, x);
    u += 0x7fff + ((u >> 16) & 1);          // RNE
    return (unsigned short)(u >> 16);
}

__global__ void prep_kernel(const float* __restrict__ params, const float* __restrict__ w1,
                            const float* __restrict__ b1, const float* __restrict__ w2,
                            char* __restrict__ wsb) {
    float* zxyT = (float*)(wsb + WSB_ZXYT);
    float* zhw  = (float*)(wsb + WSB_ZHW);
    float* Qm   = (float*)(wsb + WSB_QM);
    int t = blockIdx.x * 256 + threadIdx.x;     // grid covers 49152
    if (t < 8192) {
        int c = t >> 10, xy = t & 1023;
        float cx = 2.0f * (((xy >> 5) + 0.5f) / 32.0f) - 1.0f;
        float cy = 2.0f * (((xy & 31) + 0.5f) / 32.0f) - 1.0f;
        zxyT[t] = cx * w1[c * 4 + 0] + cy * w1[c * 4 + 1] + b1[c];
    } else if (t < 16384) {
        int u = t - 8192;
        int hw = u >> 3, c = u & 7;
        float ch = 2.0f * (((hw >> 5) + 0.5f) / 32.0f) - 1.0f;
        float cw = 2.0f * (((hw & 31) + 0.5f) / 32.0f) - 1.0f;
        zhw[u] = ch * w1[c * 4 + 2] + cw * w1[c * 4 + 3];
    } else {
        int u = t - 16384;                  // u = c*4096 + o*64 + i
        int c = u >> 12, oi = u & 4095;
        float s = 0.0f;
        #pragma unroll
        for (int n = 0; n < 16; n++)
            s += params[n * 4096 + oi] * w2[n * 8 + c];
        Qm[u] = s * (1.0f / 1024.0f);
    }
}

__global__ void vsum_kernel(const float* __restrict__ v, char* __restrict__ wsb) {
    float* Vsum = (float*)(wsb + WSB_VSUM);
    int bi = blockIdx.x, lane = threadIdx.x;
    const float* p = v + bi * 1024;
    float s = 0.0f;
    #pragma unroll
    for (int t = 0; t < 16; t++) s += p[lane + t * 64];
    #pragma unroll
    for (int off = 32; off > 0; off >>= 1) s += __shfl_down(s, off);
    if (lane == 0) Vsum[bi] = s;
}

__global__ __launch_bounds__(512) void e_kernel(const float* __restrict__ params,
                                                const float* __restrict__ b2,
                                                const float* __restrict__ conv_b,
                                                const float* __restrict__ bias,
                                                char* __restrict__ wsb) {
    const float* Vsum = (const float*)(wsb + WSB_VSUM);
    float* E = (float*)(wsb + WSB_E);
    __shared__ float Rsh[64 * 65];
    __shared__ float Vs[512];
    int t = threadIdx.x;
    float b2r[16];
    #pragma unroll
    for (int n = 0; n < 16; n++) b2r[n] = b2[n];
    for (int j = t; j < 4096; j += 512) {
        float s = 0.0f;
        #pragma unroll
        for (int n = 0; n < 16; n++) s += params[n * 4096 + j] * b2r[n];
        Rsh[(j >> 6) * 65 + (j & 63)] = s;
    }
    Vs[t] = Vsum[t];
    __syncthreads();
    int b = t >> 6, o = t & 63;
    float s = 0.0f;
    for (int i = 0; i < 64; i++) s += Rsh[o * 65 + i] * Vs[b * 64 + i];
    E[t] = conv_b[o] + bias[o] + s * (1.0f / 1024.0f);
}

// Gt[hw*8192 + c*1024 + xy] = bf16(gelu(zxyT[c,xy] + zhw[hw,c]))
__global__ __launch_bounds__(256) void g_kernel(char* __restrict__ wsb) {
    const float* zxyT = (const float*)(wsb + WSB_ZXYT);
    const float* zhw  = (const float*)(wsb + WSB_ZHW);
    unsigned short* Gt = (unsigned short*)(wsb + WSB_GT);
    int t = blockIdx.x * 256 + threadIdx.x;     // 0..2^20-1
    int seg = t >> 7;                           // (hw, c)
    int hw = seg >> 3, c = seg & 7;
    int xy0 = (t & 127) * 8;
    float zz = zhw[hw * 8 + c];
    const float* zx = zxyT + c * 1024 + xy0;
    unsigned short h[8];
    #pragma unroll
    for (int u = 0; u < 8; u++) {
        float z = zx[u] + zz;
        h[u] = f2bf(0.5f * z * (1.0f + erff(z * 0.70710678118f)));
    }
    *(uint4*)(Gt + (size_t)hw * 8192 + c * 1024 + xy0) = *(uint4*)h;
}

// P[(b*64+o)*8192 + c*1024 + xy] bf16 = sum_i Qm[c,o,i]*v[b,i,xy]  (fp32 compute)
// grid (xyc=8, c=8, b=8), block 256: tile 64o x 128xy, K=64
__global__ __launch_bounds__(256) void p_kernel(const float* __restrict__ v,
                                                char* __restrict__ wsb) {
    const float* Qm = (const float*)(wsb + WSB_QM);
    unsigned short* P = (unsigned short*)(wsb + WSB_P);
    __shared__ float Qsh[64 * 65];
    __shared__ float Vs[64 * 132];
    int xyc = blockIdx.x, c = blockIdx.y, b = blockIdx.z;
    int tid = threadIdx.x;
    for (int j = tid; j < 4096; j += 256)
        Qsh[(j >> 6) * 65 + (j & 63)] = Qm[c * 4096 + j];
    int xy0 = xyc * 128;
    // FIX(R3->R4): tile is 64 i-rows x 128 xy = 8192 floats; previous loop only
    // staged 4096, leaving i=32..63 as poison -> absmax 1.0. 32 iterations now.
    #pragma unroll
    for (int l = 0; l < 32; l++) {
        int idx = tid + l * 256;
        int i = idx >> 7, xy = idx & 127;
        Vs[i * 132 + xy] = v[b * 65536 + i * 1024 + xy0 + xy];
    }
    __syncthreads();
    int ty = tid >> 4, tx = tid & 15;           // o = ty*4..+4, xy = tx*8..+8
    float acc[4][8] = {};
    for (int i = 0; i < 64; i++) {
        float4 b0 = *(const float4*)(&Vs[i * 132 + tx * 8]);
        float4 b1 = *(const float4*)(&Vs[i * 132 + tx * 8 + 4]);
        #pragma unroll
        for (int m = 0; m < 4; m++) {
            float a = Qsh[(ty * 4 + m) * 65 + i];
            acc[m][0] += a * b0.x; acc[m][1] += a * b0.y;
            acc[m][2] += a * b0.z; acc[m][3] += a * b0.w;
            acc[m][4] += a * b1.x; acc[m][5] += a * b1.y;
            acc[m][6] += a * b1.z; acc[m][7] += a * b1.w;
        }
    }
    #pragma unroll
    for (int m = 0; m < 4; m++) {
        int bo = b * 64 + ty * 4 + m;
        unsigned short h[8];
        #pragma unroll
        for (int x = 0; x < 8; x++) h[x] = f2bf(acc[m][x]);
        *(uint4*)(P + (size_t)bo * 8192 + c * 1024 + xy0 + tx * 8) = *(uint4*)h;
    }
}

// big GEMM: part[ks] = P(512x8192) @ Gt^T over k-slice ks*512..+512
// 128x128 tile, 4 waves (2x2 of 64x64), BK=32, global_load_lds width-16 staging (m97)
__global__ __launch_bounds__(256, 2) void biggemm_kernel(char* __restrict__ wsb) {
    const unsigned short* P  = (const unsigned short*)(wsb + WSB_P);
    const unsigned short* Gt = (const unsigned short*)(wsb + WSB_GT);
    float* part = (float*)(wsb + WSB_PART);
    __shared__ unsigned short Ash[128 * 32];    // [row m][k] rows of 64B
    __shared__ unsigned short Bsh[128 * 32];    // [row n][k]
    int tid = threadIdx.x;
    int bn = blockIdx.x, bm = blockIdx.y, ks = blockIdx.z;
    int wave = tid >> 6, lane = tid & 63;
    int lr = lane & 15, quad = lane >> 4;
    int wm = wave & 1, wn = wave >> 1;
    f32x4 acc[4][4];
    #pragma unroll
    for (int mt = 0; mt < 4; mt++)
        #pragma unroll
        for (int nt = 0; nt < 4; nt++)
            acc[mt][nt] = (f32x4){0.f, 0.f, 0.f, 0.f};

    const unsigned short* Abase = P  + (size_t)(bm * 128) * 8192;
    const unsigned short* Bbase = Gt + (size_t)(bn * 128) * 8192;
    int lrow = lane >> 2;           // 0..15
    int lseg = (lane & 3) * 8;      // k elems (16B)
    int k0 = ks * 512;

    for (int kk = 0; kk < 512; kk += 32) {
        __syncthreads();
        #pragma unroll
        for (int q = 0; q < 2; q++) {
            int row = wave * 32 + q * 16 + lrow;
            __builtin_amdgcn_global_load_lds(
                (const __attribute__((address_space(1))) unsigned int*)
                    (Abase + (size_t)row * 8192 + k0 + kk + lseg),
                (__attribute__((address_space(3))) unsigned int*)
                    (Ash + wave * 1024 + q * 512),
                16, 0, 0);
            __builtin_amdgcn_global_load_lds(
                (const __attribute__((address_space(1))) unsigned int*)
                    (Bbase + (size_t)row * 8192 + k0 + kk + lseg),
                (__attribute__((address_space(3))) unsigned int*)
                    (Bsh + wave * 1024 + q * 512),
                16, 0, 0);
        }
        __syncthreads();
        bf16x8 a[4], bfr[4];
        #pragma unroll
        for (int mt = 0; mt < 4; mt++)
            a[mt] = *(bf16x8*)(&Ash[(wm * 64 + mt * 16 + lr) * 32 + quad * 8]);
        #pragma unroll
        for (int nt = 0; nt < 4; nt++)
            bfr[nt] = *(bf16x8*)(&Bsh[(wn * 64 + nt * 16 + lr) * 32 + quad * 8]);
        #pragma unroll
        for (int mt = 0; mt < 4; mt++)
            #pragma unroll
            for (int nt = 0; nt < 4; nt++)
                acc[mt][nt] = __builtin_amdgcn_mfma_f32_16x16x32_bf16(a[mt], bfr[nt], acc[mt][nt], 0, 0, 0);
    }
    float* dst = part + (size_t)ks * 524288;
    #pragma unroll
    for (int mt = 0; mt < 4; mt++) {
        #pragma unroll
        for (int nt = 0; nt < 4; nt++) {
            int n = bn * 128 + wn * 64 + nt * 16 + lr;
            #pragma unroll
            for (int r = 0; r < 4; r++) {
                int m = bm * 128 + wm * 64 + mt * 16 + quad * 4 + r;
                dst[(size_t)m * 1024 + n] = acc[mt][nt][r];
            }
        }
    }
}

// out[bo,hw] = E[b,o] + sum_i conv_w[o,i] v[b,i,hw] + sum_ks part[ks,bo,hw]
// grid (hwc=16, b=8), block 256: tile 64o x 64hw
__global__ __launch_bounds__(256) void reduce_kernel(const float* __restrict__ v,
                                                     const float* __restrict__ conv_w,
                                                     float* __restrict__ out,
                                                     char* __restrict__ wsb) {
    const float* E = (const float*)(wsb + WSB_E);
    const float* part = (const float*)(wsb + WSB_PART);
    __shared__ float Cw[64 * 65];
    __shared__ float Vs[64 * 68];
    int hwc = blockIdx.x, b = blockIdx.y;
    int tid = threadIdx.x;
    for (int j = tid; j < 4096; j += 256)
        Cw[(j >> 6) * 65 + (j & 63)] = conv_w[j];
    int hw0 = hwc * 64;
    #pragma unroll
    for (int l = 0; l < 16; l++) {
        int idx = tid + l * 256;        // 64 rows x 64 cols = 4096 = 16*256  (complete)
        int i = idx >> 6, hw = idx & 63;
        Vs[i * 68 + hw] = v[b * 65536 + i * 1024 + hw0 + hw];
    }
    __syncthreads();
    int ty = tid >> 4, tx = tid & 15;           // o = ty*4..+4, hw = tx*4..+4
    float acc[4][4];
    #pragma unroll
    for (int m = 0; m < 4; m++) {
        float e = E[b * 64 + ty * 4 + m];
        #pragma unroll
        for (int x = 0; x < 4; x++) acc[m][x] = e;
    }
    for (int i = 0; i < 64; i++) {
        float4 bv = *(const float4*)(&Vs[i * 68 + tx * 4]);
        #pragma unroll
        for (int m = 0; m < 4; m++) {
            float a = Cw[(ty * 4 + m) * 65 + i];
            acc[m][0] += a * bv.x; acc[m][1] += a * bv.y;
            acc[m][2] += a * bv.z; acc[m][3] += a * bv.w;
        }
    }
    #pragma unroll
    for (int ks = 0; ks < 16; ks++) {
        #pragma unroll
        for (int m = 0; m < 4; m++) {
            int bo = b * 64 + ty * 4 + m;
            float4 p = *(const float4*)(&part[(size_t)ks * 524288 + (size_t)bo * 1024 + hw0 + tx * 4]);
            acc[m][0] += p.x; acc[m][1] += p.y; acc[m][2] += p.z; acc[m][3] += p.w;
        }
    }
    #pragma unroll
    for (int m = 0; m < 4; m++) {
        int bo = b * 64 + ty * 4 + m;
        *(float4*)(&out[(size_t)bo * 1024 + hw0 + tx * 4]) =
            make_float4(acc[m][0], acc[m][1], acc[m][2], acc[m][3]);
    }
}

extern "C" void kernel_launch(void* const* d_in, const int* in_sizes, int n_in,
                              void* d_out, int out_size, void* d_ws, size_t ws_size,
                              hipStream_t stream) {
    const float* v      = (const float*)d_in[0];
    const float* params = (const float*)d_in[1];
    const float* w1     = (const float*)d_in[2];
    const float* b1     = (const float*)d_in[3];
    const float* w2     = (const float*)d_in[4];
    const float* b2     = (const float*)d_in[5];
    const float* conv_w = (const float*)d_in[6];
    const float* conv_b = (const float*)d_in[7];
    const float* bias   = (const float*)d_in[8];
    float* out = (float*)d_out;
    char* wsb  = (char*)d_ws;

    prep_kernel<<<192, 256, 0, stream>>>(params, w1, b1, w2, wsb);
    vsum_kernel<<<512, 64, 0, stream>>>(v, wsb);
    e_kernel<<<1, 512, 0, stream>>>(params, b2, conv_b, bias, wsb);
    g_kernel<<<4096, 256, 0, stream>>>(wsb);
    p_kernel<<<dim3(8, 8, 8), 256, 0, stream>>>(v, wsb);
    biggemm_kernel<<<dim3(8, 4, 16), 256, 0, stream>>>(wsb);
    reduce_kernel<<<dim3(16, 8), 256, 0, stream>>>(v, conv_w, out, wsb);
}

// Round 5
// 100.873 us; speedup vs baseline: 4.8159x; 1.4742x over previous
//
#include <hip/hip_runtime.h>
#include <hip/hip_bf16.h>
#include <math.h>

// B=8, CIN=64, COUT=64, N=16, H=W=32
// G[c](xy,hw) = gelu(zxy[c,xy] + zhw[c,hw]) is a function of a SUM ->
// Chebyshev interpolation in v=zhw with R=8 nodes per c (error ~1e-5):
//   gelu(u+v) ~= sum_r gelu(u + t_cr) * L_cr(v)
// Pipeline (all fp32):
//   W[b,i,cr]  = sum_xy v[b,i,xy]*Gtab[xy,cr]          (split-K 16, parts)
//   M1[b,o,cr] = sum_i  Qm[c,o,i]*W[b,i,cr]            (Qm = sum_n params*w2/1024)
//   out[b,o,hw]= sum_cr M1*Ltab[cr,hw] + sum_i conv_w[o,i]*v[b,i,hw] + E[b,o]
//   E[b,o]     = conv_b+bias + sum_i Rb2[o,i]*Vsum[b,i],  Rb2 = sum_n params*b2/1024
//
// ws layout (byte offsets):
#define WSB_ZHW   0u         // 8192 f32  zhw[c*1024+hw]
#define WSB_NODES 32768u     // 64 f32    nodes[c*8+r]
#define WSB_DEN   33024u     // 64 f32    den[cr] = prod_{s!=r}(t_r - t_s)
#define WSB_VSUM  33280u     // 512 f32   (zeroed in prep1, atomicAdd in wgemm)
#define WSB_E     35328u     // 512 f32
#define WSB_GTAB  40960u     // 1024*64 f32  Gtab[xy*64+cr] = gelu(zxy[c,xy]+t_cr)
#define WSB_LTAB  303104u    // 64*1024 f32  Ltab[cr*1024+hw]
#define WSB_QM    565248u    // 8*64*64 f32  Qm[c*4096+o*64+i]
#define WSB_RB2   696320u    // 64*64 f32
#define WSB_M1    712704u    // 8*64*64 f32  M1[b*4096+o*64+cr]
#define WSB_WPART 843776u    // 16*512*64 f32 Wpart[ks*32768+(b*64+i)*64+cr]
// total ~9.2 MB (ws is 256 MiB)

__device__ inline float gelu_exact(float z) {
    return 0.5f * z * (1.0f + erff(z * 0.70710678118f));
}

// one block: zhw table, per-c ranges -> Chebyshev nodes + denominators, zero Vsum
__global__ __launch_bounds__(256) void prep1_kernel(const float* __restrict__ w1,
                                                    char* __restrict__ wsb) {
    float* zhw_g   = (float*)(wsb + WSB_ZHW);
    float* nodes_g = (float*)(wsb + WSB_NODES);
    float* den_g   = (float*)(wsb + WSB_DEN);
    float* Vsum    = (float*)(wsb + WSB_VSUM);
    __shared__ float zsh[8192];
    __shared__ float nodesh[64];
    int t = threadIdx.x;
    #pragma unroll
    for (int l = 0; l < 32; l++) {
        int idx = t + l * 256;
        int c = idx >> 10, hw = idx & 1023;
        float ch = 2.0f * (((hw >> 5) + 0.5f) / 32.0f) - 1.0f;
        float cw = 2.0f * (((hw & 31) + 0.5f) / 32.0f) - 1.0f;
        float val = ch * w1[c * 4 + 2] + cw * w1[c * 4 + 3];
        zsh[idx] = val;
        zhw_g[idx] = val;
    }
    Vsum[t] = 0.0f;
    Vsum[t + 256] = 0.0f;
    __syncthreads();
    if (t < 8) {
        float mn = 1e30f, mx = -1e30f;
        const float4* zp = (const float4*)&zsh[t * 1024];
        for (int j = 0; j < 256; j++) {
            float4 x = zp[j];
            mn = fminf(mn, fminf(fminf(x.x, x.y), fminf(x.z, x.w)));
            mx = fmaxf(mx, fmaxf(fmaxf(x.x, x.y), fmaxf(x.z, x.w)));
        }
        float mid = 0.5f * (mn + mx);
        float hwid = fmaxf(0.5f * (mx - mn), 1e-2f);     // guard degenerate range
        #pragma unroll
        for (int r = 0; r < 8; r++) {
            float nd = mid + hwid * cosf(3.14159265358979f * (2 * r + 1) / 16.0f);
            nodesh[t * 8 + r] = nd;
            nodes_g[t * 8 + r] = nd;
        }
    }
    __syncthreads();
    if (t < 64) {
        int c = t >> 3, r = t & 7;
        float tr = nodesh[c * 8 + r];
        float d = 1.0f;
        #pragma unroll
        for (int s = 0; s < 8; s++)
            if (s != r) d *= (tr - nodesh[c * 8 + s]);
        den_g[t] = d;
    }
}

// tables: Gtab, Ltab, Qm, Rb2 — one element per thread, 656*256 = 167936
__global__ __launch_bounds__(256) void prep2_kernel(const float* __restrict__ params,
                                                    const float* __restrict__ w1,
                                                    const float* __restrict__ b1,
                                                    const float* __restrict__ w2,
                                                    const float* __restrict__ b2,
                                                    char* __restrict__ wsb) {
    const float* zhw   = (const float*)(wsb + WSB_ZHW);
    const float* nodes = (const float*)(wsb + WSB_NODES);
    const float* den   = (const float*)(wsb + WSB_DEN);
    float* Gtab = (float*)(wsb + WSB_GTAB);
    float* Ltab = (float*)(wsb + WSB_LTAB);
    float* Qm   = (float*)(wsb + WSB_QM);
    float* Rb2  = (float*)(wsb + WSB_RB2);
    int u = blockIdx.x * 256 + threadIdx.x;
    if (u < 65536) {                        // Gtab[xy*64 + cr]
        int xy = u >> 6, cr = u & 63, c = cr >> 3;
        float cx = 2.0f * (((xy >> 5) + 0.5f) / 32.0f) - 1.0f;
        float cy = 2.0f * (((xy & 31) + 0.5f) / 32.0f) - 1.0f;
        float z = cx * w1[c * 4 + 0] + cy * w1[c * 4 + 1] + b1[c] + nodes[cr];
        Gtab[u] = gelu_exact(z);
    } else if (u < 131072) {                // Ltab[cr*1024 + hw]
        int u2 = u - 65536;
        int cr = u2 >> 10, hw = u2 & 1023, c = cr >> 3, r = cr & 7;
        float vv = zhw[c * 1024 + hw];
        float p = 1.0f;
        #pragma unroll
        for (int s = 0; s < 8; s++)
            if (s != r) p *= (vv - nodes[c * 8 + s]);
        Ltab[u2] = p / den[cr];
    } else if (u < 163840) {                // Qm[c*4096 + o*64 + i]
        int u2 = u - 131072;
        int c = u2 >> 12, oi = u2 & 4095;
        float s = 0.0f;
        #pragma unroll
        for (int n = 0; n < 16; n++)
            s += params[n * 4096 + oi] * w2[n * 8 + c];
        Qm[u2] = s * (1.0f / 1024.0f);
    } else {                                // Rb2[o*64 + i]  (includes /1024)
        int oi = u - 163840;
        float s = 0.0f;
        #pragma unroll
        for (int n = 0; n < 16; n++)
            s += params[n * 4096 + oi] * b2[n];
        Rb2[oi] = s * (1.0f / 1024.0f);
    }
}

// Wpart[ks][bi][cr] = sum over xy-chunk of v[bi,xy]*Gtab[xy,cr]; also Vsum via atomics.
// grid (32 bi-tiles, 16 ks), block 256; v read exactly once (8 MB).
__global__ __launch_bounds__(256) void wgemm_kernel(const float* __restrict__ v,
                                                    char* __restrict__ wsb) {
    const float* Gtab = (const float*)(wsb + WSB_GTAB);
    float* Wpart = (float*)(wsb + WSB_WPART);
    float* Vsum  = (float*)(wsb + WSB_VSUM);
    __shared__ float Vs[16][68];
    __shared__ float Gs[64][64];
    int t = threadIdx.x;
    int bi0 = blockIdx.x * 16, xy0 = blockIdx.y * 64;
    {
        int r = t >> 4, c4 = t & 15;
        *(float4*)&Vs[r][c4 * 4] = *(const float4*)(v + (bi0 + r) * 1024 + xy0 + c4 * 4);
    }
    #pragma unroll
    for (int l = 0; l < 4; l++) {
        int e = t + l * 256;
        int xy = e >> 4, q = e & 15;
        *(float4*)&Gs[xy][q * 4] = *(const float4*)(Gtab + (size_t)(xy0 + xy) * 64 + q * 4);
    }
    __syncthreads();
    int bl = t >> 4, crq = t & 15;
    float4 acc = make_float4(0.f, 0.f, 0.f, 0.f);
    float vs = 0.0f;
    #pragma unroll 8
    for (int xy = 0; xy < 64; xy++) {
        float a = Vs[bl][xy];
        float4 g = *(const float4*)&Gs[xy][crq * 4];
        acc.x += a * g.x; acc.y += a * g.y; acc.z += a * g.z; acc.w += a * g.w;
        vs += a;
    }
    *(float4*)(Wpart + (size_t)blockIdx.y * 32768 + (bi0 + bl) * 64 + crq * 4) = acc;
    if (crq == 0) atomicAdd(&Vsum[bi0 + bl], vs);
}

// M1[b,o,cr] = sum_i Qm[c,o,i] * (sum_ks Wpart);  c==0 blocks also produce E[b,o].
// grid (c=8, b=8), block 256
__global__ __launch_bounds__(256) void m1_kernel(const float* __restrict__ conv_b,
                                                 const float* __restrict__ bias,
                                                 char* __restrict__ wsb) {
    const float* Qm    = (const float*)(wsb + WSB_QM);
    const float* Wpart = (const float*)(wsb + WSB_WPART);
    const float* Rb2   = (const float*)(wsb + WSB_RB2);
    const float* Vsum  = (const float*)(wsb + WSB_VSUM);
    float* M1 = (float*)(wsb + WSB_M1);
    float* E  = (float*)(wsb + WSB_E);
    __shared__ float Qsh[64 * 64];
    __shared__ float Wsht[8][64];
    int c = blockIdx.x, b = blockIdx.y;
    int t = threadIdx.x;
    #pragma unroll
    for (int l = 0; l < 16; l++) {
        int e = t + l * 256;
        Qsh[e] = Qm[c * 4096 + e];
    }
    #pragma unroll
    for (int l = 0; l < 2; l++) {
        int e = t + l * 256;
        int i = e >> 3, r = e & 7;
        float s = 0.0f;
        #pragma unroll
        for (int ks = 0; ks < 16; ks++)
            s += Wpart[(size_t)ks * 32768 + (b * 64 + i) * 64 + c * 8 + r];
        Wsht[r][i] = s;
    }
    __syncthreads();
    #pragma unroll
    for (int l = 0; l < 2; l++) {
        int m = t + l * 256;
        int o = m >> 3, r = m & 7;
        float acc = 0.0f;
        #pragma unroll
        for (int i4 = 0; i4 < 16; i4++) {
            float4 q = *(const float4*)&Qsh[o * 64 + i4 * 4];
            float4 w = *(const float4*)&Wsht[r][i4 * 4];
            acc += q.x * w.x + q.y * w.y + q.z * w.z + q.w * w.w;
        }
        M1[b * 4096 + o * 64 + c * 8 + r] = acc;
    }
    if (c == 0 && t < 64) {
        float s = conv_b[t] + bias[t];
        for (int i = 0; i < 64; i++)
            s += Rb2[t * 64 + i] * Vsum[b * 64 + i];
        E[b * 64 + t] = s;
    }
}

// out[b,o,hw] = E + sum_{k<64} M1[b,o,k]*Ltab[k,hw] + sum_{k<64} conv_w[o,k]*v[b,k,hw]
// grid (16 hw-tiles, 2 o-tiles, 8 b), block 256; tile 32o x 64hw, K=128
__global__ __launch_bounds__(256) void final_kernel(const float* __restrict__ v,
                                                    const float* __restrict__ conv_w,
                                                    float* __restrict__ out,
                                                    char* __restrict__ wsb) {
    const float* Ltab = (const float*)(wsb + WSB_LTAB);
    const float* M1   = (const float*)(wsb + WSB_M1);
    const float* E    = (const float*)(wsb + WSB_E);
    __shared__ float Ct[128][36];       // [k][o], stride 36 keeps 16B align for float4
    __shared__ float Ys[128][64];       // [k][hw]
    int t = threadIdx.x;
    int hw0 = blockIdx.x * 64, o0 = blockIdx.y * 32, b = blockIdx.z;
    #pragma unroll
    for (int l = 0; l < 16; l++) {
        int e = t + l * 256;
        int ol = e >> 7, k = e & 127;
        float val = (k < 64) ? M1[b * 4096 + (o0 + ol) * 64 + k]
                             : conv_w[(o0 + ol) * 64 + (k - 64)];
        Ct[k][ol] = val;
    }
    #pragma unroll
    for (int l = 0; l < 8; l++) {
        int f = t + l * 256;
        int k = f >> 4, q = f & 15;
        const float* src = (k < 64) ? (Ltab + (size_t)k * 1024)
                                    : (v + (size_t)b * 65536 + (k - 64) * 1024);
        *(float4*)&Ys[k][q * 4] = *(const float4*)(src + hw0 + q * 4);
    }
    __syncthreads();
    int ty = t >> 5, tx = t & 31;       // o-quad, hw-pair
    float acc[4][2];
    #pragma unroll
    for (int m = 0; m < 4; m++) {
        float e = E[b * 64 + o0 + ty * 4 + m];
        acc[m][0] = e; acc[m][1] = e;
    }
    #pragma unroll 4
    for (int k = 0; k < 128; k++) {
        float4 cq = *(const float4*)&Ct[k][ty * 4];
        float2 y = *(const float2*)&Ys[k][tx * 2];
        acc[0][0] += cq.x * y.x; acc[0][1] += cq.x * y.y;
        acc[1][0] += cq.y * y.x; acc[1][1] += cq.y * y.y;
        acc[2][0] += cq.z * y.x; acc[2][1] += cq.z * y.y;
        acc[3][0] += cq.w * y.x; acc[3][1] += cq.w * y.y;
    }
    #pragma unroll
    for (int m = 0; m < 4; m++) {
        float2 r = make_float2(acc[m][0], acc[m][1]);
        *(float2*)(out + (size_t)b * 65536 + (o0 + ty * 4 + m) * 1024 + hw0 + tx * 2) = r;
    }
}

extern "C" void kernel_launch(void* const* d_in, const int* in_sizes, int n_in,
                              void* d_out, int out_size, void* d_ws, size_t ws_size,
                              hipStream_t stream) {
    const float* v      = (const float*)d_in[0];
    const float* params = (const float*)d_in[1];
    const float* w1     = (const float*)d_in[2];
    const float* b1     = (const float*)d_in[3];
    const float* w2     = (const float*)d_in[4];
    const float* b2     = (const float*)d_in[5];
    const float* conv_w = (const float*)d_in[6];
    const float* conv_b = (const float*)d_in[7];
    const float* bias   = (const float*)d_in[8];
    float* out = (float*)d_out;
    char* wsb  = (char*)d_ws;

    prep1_kernel<<<1, 256, 0, stream>>>(w1, wsb);
    prep2_kernel<<<656, 256, 0, stream>>>(params, w1, b1, w2, b2, wsb);
    wgemm_kernel<<<dim3(32, 16), 256, 0, stream>>>(v, wsb);
    m1_kernel<<<dim3(8, 8), 256, 0, stream>>>(conv_b, bias, wsb);
    final_kernel<<<dim3(16, 2, 8), 256, 0, stream>>>(v, conv_w, out, wsb);
}

// Round 6
// 94.548 us; speedup vs baseline: 5.1382x; 1.0669x over previous
//
#include <hip/hip_runtime.h>
#include <hip/hip_bf16.h>
#include <math.h>

// B=8, CIN=64, COUT=64, N=16, H=W=32
// G[c](xy,hw) = gelu(zxy[c,xy] + zhw[c,hw]) is a function of a SUM ->
// Chebyshev interpolation in vv=zhw with R=8 nodes per c (err ~1e-5):
//   gelu(u+vv) ~= sum_r gelu(u + t_cr) * L_cr(vv)
// zhw range is analytic: ch,cw in +/-[1/32,31/32] -> symmetric, hwid=(|w1c2|+|w1c3|)*31/32.
// Pipeline (all fp32, 3 kernels):
//   prep : Gtab[xy,cr]=gelu(zxy+t_cr); Ltab[cr,hw]=Lagrange(zhw); Qm; Rb2; Vsum=0
//   wgemm: Wpart[ks,bi,cr] = sum_{xy in ks-chunk} v*Gtab; Vsum += row-sums (atomic)
//   final: M1[o,cr]=Qm@(sum_ks Wpart); E=conv_b+bias+Rb2@Vsum;
//          out = M1@Ltab + conv_w@v + E      (single 128-deep K loop)
//
// ws layout (byte offsets):
#define WSB_VSUM  0u         // 512 f32   (zeroed in prep, atomicAdd in wgemm)
#define WSB_GTAB  4096u      // 1024*64 f32  Gtab[xy*64+cr]
#define WSB_LTAB  266240u    // 64*1024 f32  Ltab[cr*1024+hw]
#define WSB_QM    528384u    // 8*64*64 f32  Qm[c*4096+o*64+i] (= sum_n params*w2 /1024)
#define WSB_RB2   659456u    // 64*64 f32    (= sum_n params*b2 /1024)
#define WSB_WPART 675840u    // 16*512*64 f32 Wpart[ks*32768 + (b*64+i)*64 + cr]
// total ~2.8 MB (ws is 256 MiB)

#define COS8_INIT {0.98078528f, 0.83146961f, 0.55557023f, 0.19509032f, \
                  -0.19509032f, -0.55557023f, -0.83146961f, -0.98078528f}

__device__ inline float gelu_exact(float z) {
    return 0.5f * z * (1.0f + erff(z * 0.70710678118f));
}

__device__ inline float cheb_hwid(const float* w1, int c) {
    return fmaxf((fabsf(w1[c * 4 + 2]) + fabsf(w1[c * 4 + 3])) * (31.0f / 32.0f), 1e-2f);
}

// All tables in one pass; grid 658*256 = 168448 covers 167936 table elems + 512 Vsum zeros.
__global__ __launch_bounds__(256) void prep_kernel(const float* __restrict__ params,
                                                   const float* __restrict__ w1,
                                                   const float* __restrict__ b1,
                                                   const float* __restrict__ w2,
                                                   const float* __restrict__ b2,
                                                   char* __restrict__ wsb) {
    const float COS8[8] = COS8_INIT;
    float* Gtab = (float*)(wsb + WSB_GTAB);
    float* Ltab = (float*)(wsb + WSB_LTAB);
    float* Qm   = (float*)(wsb + WSB_QM);
    float* Rb2  = (float*)(wsb + WSB_RB2);
    float* Vsum = (float*)(wsb + WSB_VSUM);
    int u = blockIdx.x * 256 + threadIdx.x;
    if (u < 65536) {                        // Gtab[xy*64 + cr]
        int xy = u >> 6, cr = u & 63, c = cr >> 3, r = cr & 7;
        float cx = 2.0f * (((xy >> 5) + 0.5f) / 32.0f) - 1.0f;
        float cy = 2.0f * (((xy & 31) + 0.5f) / 32.0f) - 1.0f;
        float z = cx * w1[c * 4 + 0] + cy * w1[c * 4 + 1] + b1[c]
                + cheb_hwid(w1, c) * COS8[r];
        Gtab[u] = gelu_exact(z);
    } else if (u < 131072) {                // Ltab[cr*1024 + hw]
        int u2 = u - 65536;
        int cr = u2 >> 10, hw = u2 & 1023, c = cr >> 3, r = cr & 7;
        float hwid = cheb_hwid(w1, c);
        float ch = 2.0f * (((hw >> 5) + 0.5f) / 32.0f) - 1.0f;
        float cw = 2.0f * (((hw & 31) + 0.5f) / 32.0f) - 1.0f;
        float vv = ch * w1[c * 4 + 2] + cw * w1[c * 4 + 3];
        float tr = hwid * COS8[r];
        float p = 1.0f, d = 1.0f;
        #pragma unroll
        for (int s = 0; s < 8; s++)
            if (s != r) {
                float ts = hwid * COS8[s];
                p *= (vv - ts);
                d *= (tr - ts);
            }
        Ltab[u2] = p / d;
    } else if (u < 163840) {                // Qm[c*4096 + o*64 + i]
        int u2 = u - 131072;
        int c = u2 >> 12, oi = u2 & 4095;
        float s = 0.0f;
        #pragma unroll
        for (int n = 0; n < 16; n++)
            s += params[n * 4096 + oi] * w2[n * 8 + c];
        Qm[u2] = s * (1.0f / 1024.0f);
    } else if (u < 167936) {                // Rb2[o*64 + i]  (includes /1024)
        int oi = u - 163840;
        float s = 0.0f;
        #pragma unroll
        for (int n = 0; n < 16; n++)
            s += params[n * 4096 + oi] * b2[n];
        Rb2[oi] = s * (1.0f / 1024.0f);
    } else {
        Vsum[u - 167936] = 0.0f;            // 512 entries
    }
}

// Wpart[ks][bi][cr] = sum over 64-xy chunk of v[bi,xy]*Gtab[xy,cr]; Vsum via atomics.
// grid (32 bi-tiles, 16 ks), block 256; v read exactly once (8 MB).
__global__ __launch_bounds__(256) void wgemm_kernel(const float* __restrict__ v,
                                                    char* __restrict__ wsb) {
    const float* Gtab = (const float*)(wsb + WSB_GTAB);
    float* Wpart = (float*)(wsb + WSB_WPART);
    float* Vsum  = (float*)(wsb + WSB_VSUM);
    __shared__ float Vs[16][68];
    __shared__ float Gs[64][64];
    int t = threadIdx.x;
    int bi0 = blockIdx.x * 16, xy0 = blockIdx.y * 64;
    {
        int r = t >> 4, c4 = t & 15;
        *(float4*)&Vs[r][c4 * 4] = *(const float4*)(v + (bi0 + r) * 1024 + xy0 + c4 * 4);
    }
    #pragma unroll
    for (int l = 0; l < 4; l++) {
        int e = t + l * 256;
        int xy = e >> 4, q = e & 15;
        *(float4*)&Gs[xy][q * 4] = *(const float4*)(Gtab + (size_t)(xy0 + xy) * 64 + q * 4);
    }
    __syncthreads();
    int bl = t >> 4, crq = t & 15;
    float4 acc = make_float4(0.f, 0.f, 0.f, 0.f);
    float vs = 0.0f;
    #pragma unroll 8
    for (int xy = 0; xy < 64; xy++) {
        float a = Vs[bl][xy];
        float4 g = *(const float4*)&Gs[xy][crq * 4];
        acc.x += a * g.x; acc.y += a * g.y; acc.z += a * g.z; acc.w += a * g.w;
        vs += a;
    }
    *(float4*)(Wpart + (size_t)blockIdx.y * 32768 + (bi0 + bl) * 64 + crq * 4) = acc;
    if (crq == 0) atomicAdd(&Vsum[bi0 + bl], vs);
}

// Fused M1 + E + output GEMM.
// grid (16 hw-tiles, 2 o-tiles, 8 b), block 256; tile 32o x 64hw, K=128.
// LDS: Ct[128][36] (k<64: M1, k>=64: conv_w) + Ys[128][64] (k<64: Ltab, k>=64: v rows).
// Wsum (64i x 64cr) aliases Ys rows 0..63 (consumed before Ltab overwrite, barriered).
__global__ __launch_bounds__(256) void final_kernel(const float* __restrict__ v,
                                                    const float* __restrict__ conv_w,
                                                    const float* __restrict__ conv_b,
                                                    const float* __restrict__ bias,
                                                    float* __restrict__ out,
                                                    char* __restrict__ wsb) {
    const float* Ltab  = (const float*)(wsb + WSB_LTAB);
    const float* Qm    = (const float*)(wsb + WSB_QM);
    const float* Rb2   = (const float*)(wsb + WSB_RB2);
    const float* Vsum  = (const float*)(wsb + WSB_VSUM);
    const float* Wpart = (const float*)(wsb + WSB_WPART);
    __shared__ float smem[128 * 36 + 128 * 64];     // 51.2 KB
    __shared__ float Esh[32];
    float* Ct = smem;                   // [k][o] stride 36
    float* Ys = smem + 128 * 36;        // [k][hw] stride 64
    float* Wsum = Ys;                   // alias: 64*64 floats (rows 0..63 of Ys)
    int t = threadIdx.x;
    int hw0 = blockIdx.x * 64, o0 = blockIdx.y * 32, b = blockIdx.z;

    // --- stage 1: Wsum (sum_ks Wpart), conv_w rows of Ct, v rows of Ys ---
    {
        int e0 = t * 16;                // Wsum elems e = i*64+cr, 16 per thread
        float4 a0 = {0,0,0,0}, a1 = {0,0,0,0}, a2 = {0,0,0,0}, a3 = {0,0,0,0};
        const float* wp = Wpart + b * 4096 + e0;
        #pragma unroll
        for (int ks = 0; ks < 16; ks++) {
            const float4* p = (const float4*)(wp + (size_t)ks * 32768);
            float4 x0 = p[0], x1 = p[1], x2 = p[2], x3 = p[3];
            a0.x += x0.x; a0.y += x0.y; a0.z += x0.z; a0.w += x0.w;
            a1.x += x1.x; a1.y += x1.y; a1.z += x1.z; a1.w += x1.w;
            a2.x += x2.x; a2.y += x2.y; a2.z += x2.z; a2.w += x2.w;
            a3.x += x3.x; a3.y += x3.y; a3.z += x3.z; a3.w += x3.w;
        }
        *(float4*)&Wsum[e0]      = a0;
        *(float4*)&Wsum[e0 + 4]  = a1;
        *(float4*)&Wsum[e0 + 8]  = a2;
        *(float4*)&Wsum[e0 + 12] = a3;
    }
    #pragma unroll
    for (int l = 0; l < 8; l++) {       // Ct rows 64..127 <- conv_w
        int e = t + l * 256;            // 2048 = 64 kk x 32 ol
        int kk = e >> 5, ol = e & 31;
        Ct[(64 + kk) * 36 + ol] = conv_w[(o0 + ol) * 64 + kk];
    }
    #pragma unroll
    for (int l = 0; l < 4; l++) {       // Ys rows 64..127 <- v (does NOT alias Wsum)
        int f = t + l * 256;            // 1024 float4s = 64 rows x 64 hw
        int k = f >> 4, q = f & 15;
        *(float4*)&Ys[(64 + k) * 64 + q * 4] =
            *(const float4*)(v + (size_t)b * 65536 + k * 1024 + hw0 + q * 4);
    }
    __syncthreads();

    // --- stage 2: M1 -> Ct rows 0..63; E -> Esh ---
    {
        int ol = t >> 3, c = t & 7;     // o = o0+ol, cr = c*8..c*8+7
        float a[8] = {};
        const float* qrow = Qm + c * 4096 + (o0 + ol) * 64;
        for (int i = 0; i < 64; i++) {
            float q = qrow[i];
            float4 w0 = *(const float4*)&Wsum[i * 64 + c * 8];
            float4 w1v = *(const float4*)&Wsum[i * 64 + c * 8 + 4];
            a[0] += q * w0.x; a[1] += q * w0.y; a[2] += q * w0.z; a[3] += q * w0.w;
            a[4] += q * w1v.x; a[5] += q * w1v.y; a[6] += q * w1v.z; a[7] += q * w1v.w;
        }
        #pragma unroll
        for (int r = 0; r < 8; r++)
            Ct[(c * 8 + r) * 36 + ol] = a[r];
    }
    if (t < 32) {
        int o = o0 + t;
        float s = conv_b[o] + bias[o];
        const float* rr = Rb2 + o * 64;
        const float* vs = Vsum + b * 64;
        for (int i = 0; i < 64; i++) s += rr[i] * vs[i];
        Esh[t] = s;
    }
    __syncthreads();

    // --- stage 3: Ys rows 0..63 <- Ltab (overwrites Wsum; consumed above) ---
    #pragma unroll
    for (int l = 0; l < 4; l++) {
        int f = t + l * 256;
        int k = f >> 4, q = f & 15;
        *(float4*)&Ys[k * 64 + q * 4] =
            *(const float4*)(Ltab + (size_t)k * 1024 + hw0 + q * 4);
    }
    __syncthreads();

    // --- stage 4: out = Ct^T @ Ys + E ---
    int ty = t >> 5, tx = t & 31;       // o = o0+ty*4+m, hw = hw0+tx*2+{0,1}
    float acc[4][2];
    #pragma unroll
    for (int m = 0; m < 4; m++) {
        float e = Esh[ty * 4 + m];
        acc[m][0] = e; acc[m][1] = e;
    }
    #pragma unroll 4
    for (int k = 0; k < 128; k++) {
        float4 cq = *(const float4*)&Ct[k * 36 + ty * 4];
        float2 y = *(const float2*)&Ys[k * 64 + tx * 2];
        acc[0][0] += cq.x * y.x; acc[0][1] += cq.x * y.y;
        acc[1][0] += cq.y * y.x; acc[1][1] += cq.y * y.y;
        acc[2][0] += cq.z * y.x; acc[2][1] += cq.z * y.y;
        acc[3][0] += cq.w * y.x; acc[3][1] += cq.w * y.y;
    }
    #pragma unroll
    for (int m = 0; m < 4; m++) {
        float2 r = make_float2(acc[m][0], acc[m][1]);
        *(float2*)(out + (size_t)b * 65536 + (o0 + ty * 4 + m) * 1024 + hw0 + tx * 2) = r;
    }
}

extern "C" void kernel_launch(void* const* d_in, const int* in_sizes, int n_in,
                              void* d_out, int out_size, void* d_ws, size_t ws_size,
                              hipStream_t stream) {
    const float* v      = (const float*)d_in[0];
    const float* params = (const float*)d_in[1];
    const float* w1     = (const float*)d_in[2];
    const float* b1     = (const float*)d_in[3];
    const float* w2     = (const float*)d_in[4];
    const float* b2     = (const float*)d_in[5];
    const float* conv_w = (const float*)d_in[6];
    const float* conv_b = (const float*)d_in[7];
    const float* bias   = (const float*)d_in[8];
    float* out = (float*)d_out;
    char* wsb  = (char*)d_ws;

    prep_kernel<<<658, 256, 0, stream>>>(params, w1, b1, w2, b2, wsb);
    wgemm_kernel<<<dim3(32, 16), 256, 0, stream>>>(v, wsb);
    final_kernel<<<dim3(16, 2, 8), 256, 0, stream>>>(v, conv_w, conv_b, bias, out, wsb);
}

// Round 7
// 92.683 us; speedup vs baseline: 5.2415x; 1.0201x over previous
//
#include <hip/hip_runtime.h>
#include <hip/hip_bf16.h>
#include <math.h>

// B=8, CIN=64, COUT=64, N=16, H=W=32
// G[c](xy,hw) = gelu(zxy[c,xy] + zhw[c,hw]) is a function of a SUM ->
// Chebyshev interpolation in vv=zhw with R=8 nodes per c (err ~1e-5):
//   gelu(u+vv) ~= sum_r gelu(u + t_cr) * L_cr(vv)
// zhw range analytic: ch,cw in +/-[1/32,31/32] -> symmetric, hwid=(|w1c2|+|w1c3|)*31/32.
// TWO kernels (dispatch count is now a first-order cost; harness ws-poison fill
// ~42us dominates the timed window and is not controllable):
//   wgemm: per-block Gs tile = gelu(zxy + t_cr) generated in LDS (no global Gtab);
//          Wpart[ks,bi,cr] = sum_{xy chunk} v*Gs; VsumPart[ks,bi] = row sums;
//          plus a 200-elem slice/block of the global tables (Ltab, Qm, Rb2).
//   final: Wsum = sum_ks Wpart; M1 = Qm@Wsum; E = conv_b+bias+Rb2@(sum_ks VsumPart);
//          out = M1@Ltab + conv_w@v + E    (single 128-deep K loop)
//
// ws layout (byte offsets):
#define WSB_LTAB  0u         // 64*1024 f32  Ltab[cr*1024+hw]
#define WSB_QM    262144u    // 8*64*64 f32  Qm[c*4096+o*64+i] (= sum_n params*w2 /1024)
#define WSB_RB2   393216u    // 64*64 f32    (= sum_n params*b2 /1024)
#define WSB_WPART 409600u    // 16*512*64 f32 Wpart[ks*32768 + (b*64+i)*64 + cr]
#define WSB_VSUMP 2506752u   // 16*512 f32   VsumPart[ks*512 + bi]
// total ~2.5 MB (ws is 256 MiB)

#define COS8_INIT {0.98078528f, 0.83146961f, 0.55557023f, 0.19509032f, \
                  -0.19509032f, -0.55557023f, -0.83146961f, -0.98078528f}

__device__ inline float gelu_exact(float z) {
    return 0.5f * z * (1.0f + erff(z * 0.70710678118f));
}

__device__ inline float cheb_hwid(const float* w1, int c) {
    return fmaxf((fabsf(w1[c * 4 + 2]) + fabsf(w1[c * 4 + 3])) * (31.0f / 32.0f), 1e-2f);
}

// grid (32 bi-tiles, 16 xy-chunks), block 256; v read exactly once (8 MB).
__global__ __launch_bounds__(256) void wgemm_kernel(const float* __restrict__ v,
                                                    const float* __restrict__ params,
                                                    const float* __restrict__ w1,
                                                    const float* __restrict__ b1,
                                                    const float* __restrict__ w2,
                                                    const float* __restrict__ b2,
                                                    char* __restrict__ wsb) {
    const float COS8[8] = COS8_INIT;
    float* Ltab  = (float*)(wsb + WSB_LTAB);
    float* Qm    = (float*)(wsb + WSB_QM);
    float* Rb2   = (float*)(wsb + WSB_RB2);
    float* Wpart = (float*)(wsb + WSB_WPART);
    float* VsumP = (float*)(wsb + WSB_VSUMP);
    __shared__ float Vs[16][68];
    __shared__ float Gs[64][64];
    int t = threadIdx.x;
    int bi0 = blockIdx.x * 16, xy0 = blockIdx.y * 64;
    {   // stage 16 v rows x 64 xy
        int r = t >> 4, c4 = t & 15;
        *(float4*)&Vs[r][c4 * 4] = *(const float4*)(v + (bi0 + r) * 1024 + xy0 + c4 * 4);
    }
    // generate Gs[xyl][cr] = gelu(zxy[c, xy0+xyl] + node_cr) in LDS (16 gelu/thread)
    #pragma unroll
    for (int l = 0; l < 16; l++) {
        int e = t + l * 256;                // 4096 = 64 xyl x 64 cr
        int xyl = e >> 6, cr = e & 63, c = cr >> 3, r = cr & 7;
        int xy = xy0 + xyl;
        float cx = 2.0f * (((xy >> 5) + 0.5f) / 32.0f) - 1.0f;
        float cy = 2.0f * (((xy & 31) + 0.5f) / 32.0f) - 1.0f;
        float z = cx * w1[c * 4 + 0] + cy * w1[c * 4 + 1] + b1[c]
                + cheb_hwid(w1, c) * COS8[r];
        Gs[xyl][cr] = gelu_exact(z);
    }
    __syncthreads();
    int bl = t >> 4, crq = t & 15;
    float4 acc = make_float4(0.f, 0.f, 0.f, 0.f);
    float vs = 0.0f;
    #pragma unroll 8
    for (int xy = 0; xy < 64; xy++) {
        float a = Vs[bl][xy];
        float4 g = *(const float4*)&Gs[xy][crq * 4];
        acc.x += a * g.x; acc.y += a * g.y; acc.z += a * g.z; acc.w += a * g.w;
        vs += a;
    }
    *(float4*)(Wpart + (size_t)blockIdx.y * 32768 + (bi0 + bl) * 64 + crq * 4) = acc;
    if (crq == 0) VsumP[blockIdx.y * 512 + bi0 + bl] = vs;

    // table slice: 512 blocks x 200 elems covers Ltab(65536)+Qm(32768)+Rb2(4096)=102400
    int bid = blockIdx.y * 32 + blockIdx.x;
    int u = bid * 200 + t;
    if (t < 200) {
        if (u < 65536) {                    // Ltab[cr*1024 + hw]
            int cr = u >> 10, hw = u & 1023, c = cr >> 3, r = cr & 7;
            float hwid = cheb_hwid(w1, c);
            float ch = 2.0f * (((hw >> 5) + 0.5f) / 32.0f) - 1.0f;
            float cw = 2.0f * (((hw & 31) + 0.5f) / 32.0f) - 1.0f;
            float vv = ch * w1[c * 4 + 2] + cw * w1[c * 4 + 3];
            float tr = hwid * COS8[r];
            float p = 1.0f, d = 1.0f;
            #pragma unroll
            for (int s = 0; s < 8; s++)
                if (s != r) {
                    float ts = hwid * COS8[s];
                    p *= (vv - ts);
                    d *= (tr - ts);
                }
            Ltab[u] = p / d;
        } else if (u < 98304) {             // Qm[c*4096 + o*64 + i]
            int u2 = u - 65536;
            int c = u2 >> 12, oi = u2 & 4095;
            float s = 0.0f;
            #pragma unroll
            for (int n = 0; n < 16; n++)
                s += params[n * 4096 + oi] * w2[n * 8 + c];
            Qm[u2] = s * (1.0f / 1024.0f);
        } else {                            // Rb2[o*64 + i]
            int oi = u - 98304;
            float s = 0.0f;
            #pragma unroll
            for (int n = 0; n < 16; n++)
                s += params[n * 4096 + oi] * b2[n];
            Rb2[oi] = s * (1.0f / 1024.0f);
        }
    }
}

// Fused M1 + E + output GEMM.
// grid (16 hw-tiles, 2 o-tiles, 8 b), block 256; tile 32o x 64hw, K=128.
// LDS: Ct[128][36] (k<64: M1, k>=64: conv_w) + Ys[128][64] (k<64: Ltab, k>=64: v rows).
// Wsum (64i x 64cr) aliases Ys rows 0..63 (consumed before Ltab overwrite, barriered).
__global__ __launch_bounds__(256) void final_kernel(const float* __restrict__ v,
                                                    const float* __restrict__ conv_w,
                                                    const float* __restrict__ conv_b,
                                                    const float* __restrict__ bias,
                                                    float* __restrict__ out,
                                                    char* __restrict__ wsb) {
    const float* Ltab  = (const float*)(wsb + WSB_LTAB);
    const float* Qm    = (const float*)(wsb + WSB_QM);
    const float* Rb2   = (const float*)(wsb + WSB_RB2);
    const float* Wpart = (const float*)(wsb + WSB_WPART);
    const float* VsumP = (const float*)(wsb + WSB_VSUMP);
    __shared__ float smem[128 * 36 + 128 * 64];     // 51.2 KB
    __shared__ float Esh[32];
    __shared__ float Vsh[64];
    float* Ct = smem;                   // [k][o] stride 36
    float* Ys = smem + 128 * 36;        // [k][hw] stride 64
    float* Wsum = Ys;                   // alias: 64*64 floats (rows 0..63 of Ys)
    int t = threadIdx.x;
    int hw0 = blockIdx.x * 64, o0 = blockIdx.y * 32, b = blockIdx.z;

    // --- stage 1: Wsum (sum_ks Wpart), Vsh (sum_ks VsumP), conv_w/v staging ---
    {
        int e0 = t * 16;                // Wsum elems e = i*64+cr, 16 per thread
        float4 a0 = {0,0,0,0}, a1 = {0,0,0,0}, a2 = {0,0,0,0}, a3 = {0,0,0,0};
        const float* wp = Wpart + b * 4096 + e0;
        #pragma unroll
        for (int ks = 0; ks < 16; ks++) {
            const float4* p = (const float4*)(wp + (size_t)ks * 32768);
            float4 x0 = p[0], x1 = p[1], x2 = p[2], x3 = p[3];
            a0.x += x0.x; a0.y += x0.y; a0.z += x0.z; a0.w += x0.w;
            a1.x += x1.x; a1.y += x1.y; a1.z += x1.z; a1.w += x1.w;
            a2.x += x2.x; a2.y += x2.y; a2.z += x2.z; a2.w += x2.w;
            a3.x += x3.x; a3.y += x3.y; a3.z += x3.z; a3.w += x3.w;
        }
        *(float4*)&Wsum[e0]      = a0;
        *(float4*)&Wsum[e0 + 4]  = a1;
        *(float4*)&Wsum[e0 + 8]  = a2;
        *(float4*)&Wsum[e0 + 12] = a3;
    }
    if (t < 64) {
        float s = 0.0f;
        #pragma unroll
        for (int ks = 0; ks < 16; ks++) s += VsumP[ks * 512 + b * 64 + t];
        Vsh[t] = s;
    }
    #pragma unroll
    for (int l = 0; l < 8; l++) {       // Ct rows 64..127 <- conv_w
        int e = t + l * 256;            // 2048 = 64 kk x 32 ol
        int kk = e >> 5, ol = e & 31;
        Ct[(64 + kk) * 36 + ol] = conv_w[(o0 + ol) * 64 + kk];
    }
    #pragma unroll
    for (int l = 0; l < 4; l++) {       // Ys rows 64..127 <- v (does NOT alias Wsum)
        int f = t + l * 256;            // 1024 float4s = 64 rows x 64 hw
        int k = f >> 4, q = f & 15;
        *(float4*)&Ys[(64 + k) * 64 + q * 4] =
            *(const float4*)(v + (size_t)b * 65536 + k * 1024 + hw0 + q * 4);
    }
    __syncthreads();

    // --- stage 2: M1 -> Ct rows 0..63; E -> Esh ---
    {
        int ol = t >> 3, c = t & 7;     // o = o0+ol, cr = c*8..c*8+7
        float a[8] = {};
        const float* qrow = Qm + c * 4096 + (o0 + ol) * 64;
        for (int i = 0; i < 64; i++) {
            float q = qrow[i];
            float4 w0 = *(const float4*)&Wsum[i * 64 + c * 8];
            float4 w1v = *(const float4*)&Wsum[i * 64 + c * 8 + 4];
            a[0] += q * w0.x; a[1] += q * w0.y; a[2] += q * w0.z; a[3] += q * w0.w;
            a[4] += q * w1v.x; a[5] += q * w1v.y; a[6] += q * w1v.z; a[7] += q * w1v.w;
        }
        #pragma unroll
        for (int r = 0; r < 8; r++)
            Ct[(c * 8 + r) * 36 + ol] = a[r];
    }
    if (t < 32) {
        int o = o0 + t;
        float s = conv_b[o] + bias[o];
        const float* rr = Rb2 + o * 64;
        for (int i = 0; i < 64; i++) s += rr[i] * Vsh[i];
        Esh[t] = s;
    }
    __syncthreads();

    // --- stage 3: Ys rows 0..63 <- Ltab (overwrites Wsum; consumed above) ---
    #pragma unroll
    for (int l = 0; l < 4; l++) {
        int f = t + l * 256;
        int k = f >> 4, q = f & 15;
        *(float4*)&Ys[k * 64 + q * 4] =
            *(const float4*)(Ltab + (size_t)k * 1024 + hw0 + q * 4);
    }
    __syncthreads();

    // --- stage 4: out = Ct^T @ Ys + E ---
    int ty = t >> 5, tx = t & 31;       // o = o0+ty*4+m, hw = hw0+tx*2+{0,1}
    float acc[4][2];
    #pragma unroll
    for (int m = 0; m < 4; m++) {
        float e = Esh[ty * 4 + m];
        acc[m][0] = e; acc[m][1] = e;
    }
    #pragma unroll 4
    for (int k = 0; k < 128; k++) {
        float4 cq = *(const float4*)&Ct[k * 36 + ty * 4];
        float2 y = *(const float2*)&Ys[k * 64 + tx * 2];
        acc[0][0] += cq.x * y.x; acc[0][1] += cq.x * y.y;
        acc[1][0] += cq.y * y.x; acc[1][1] += cq.y * y.y;
        acc[2][0] += cq.z * y.x; acc[2][1] += cq.z * y.y;
        acc[3][0] += cq.w * y.x; acc[3][1] += cq.w * y.y;
    }
    #pragma unroll
    for (int m = 0; m < 4; m++) {
        float2 r = make_float2(acc[m][0], acc[m][1]);
        *(float2*)(out + (size_t)b * 65536 + (o0 + ty * 4 + m) * 1024 + hw0 + tx * 2) = r;
    }
}

extern "C" void kernel_launch(void* const* d_in, const int* in_sizes, int n_in,
                              void* d_out, int out_size, void* d_ws, size_t ws_size,
                              hipStream_t stream) {
    const float* v      = (const float*)d_in[0];
    const float* params = (const float*)d_in[1];
    const float* w1     = (const float*)d_in[2];
    const float* b1     = (const float*)d_in[3];
    const float* w2     = (const float*)d_in[4];
    const float* b2     = (const float*)d_in[5];
    const float* conv_w = (const float*)d_in[6];
    const float* conv_b = (const float*)d_in[7];
    const float* bias   = (const float*)d_in[8];
    float* out = (float*)d_out;
    char* wsb  = (char*)d_ws;

    wgemm_kernel<<<dim3(32, 16), 256, 0, stream>>>(v, params, w1, b1, w2, b2, wsb);
    final_kernel<<<dim3(16, 2, 8), 256, 0, stream>>>(v, conv_w, conv_b, bias, out, wsb);
}